// Round 2
// baseline (322.010 us; speedup 1.0000x reference)
//
#include <hip/hip_runtime.h>

// Tiny pre-kernel: filter sums -> ws[0..3] = {sum(gl), sum(gh), sum(fl), sum(fh)}
__global__ void qwt_sums_kernel(const float* __restrict__ gl, const float* __restrict__ gh,
                                const float* __restrict__ fl, const float* __restrict__ fh,
                                float* __restrict__ ws) {
    int t = threadIdx.x;
    if (t < 4) {
        const float* p = (t == 0) ? gl : (t == 1) ? gh : (t == 2) ? fl : fh;
        float s = 0.f;
        #pragma unroll
        for (int i = 0; i < 16; i++) s += p[i];
        ws[t] = s;
    }
}

// Block = 256 threads = 4 waves -> 4 consecutive output rows of one (b,c) plane.
// Stage the 10 needed source rows in LDS (coalesced float4 global loads),
// then each wave does the separable 4-tap from LDS.
// LDS layout swizzle: float col c stored at c + (c>>5)  (+1 pad float per 32)
// -> stride-8 reads (c = 8*lane) hit all 32 banks exactly twice per wave (free).
#define LSTRIDE 528  // 512 + 16 pad floats per row

__global__ __launch_bounds__(256) void qwt_main_kernel(const float* __restrict__ img,
                                                       const float* __restrict__ ws,
                                                       float* __restrict__ out) {
    __shared__ float lds[10 * LSTRIDE];  // 21,120 B

    const float w0 = -0.09375f, w1 = 0.59375f;  // CUBIC_W = {w0, w1, w1, w0}

    int tid = threadIdx.x;
    int blk = blockIdx.x;            // 0..4095
    int bc  = blk >> 6;              // 0..63 = b*16 + c   (64 blocks per plane)
    int y0  = (blk & 63) << 2;       // first output row of this block

    float sg = ws[0], sh = ws[1], sfl = ws[2], sfh = ws[3];

    const float* src = img + (size_t)bc * (512 * 512);
    int srow_base = 2 * y0 - 1;

    // ---- stage 10 source rows (10*128 float4 = 1280, 5 per thread) ----
    #pragma unroll
    for (int it = 0; it < 5; it++) {
        int i   = it * 256 + tid;        // 0..1279
        int row = i >> 7;                // 0..9
        int c4  = (i & 127) << 2;        // 0,4,...,508
        int sr  = srow_base + row;
        sr = sr < 0 ? 0 : (sr > 511 ? 511 : sr);
        float4 v = *(const float4*)(src + (size_t)sr * 512 + c4);
        float* d = lds + row * LSTRIDE + c4 + (c4 >> 5);
        d[0] = v.x; d[1] = v.y; d[2] = v.z; d[3] = v.w;   // b32 writes: conflict-free
    }
    __syncthreads();

    // ---- compute: wave w -> output row y0+w ----
    int lane = tid & 63;
    int w    = tid >> 6;           // 0..3
    int y    = y0 + w;
    int x0   = lane << 2;          // 4 output px per lane

    // clamped+swizzled source columns 2*x0-1 .. 2*x0+8
    int scol[10];
    #pragma unroll
    for (int k = 0; k < 10; k++) {
        int cc = 2 * x0 - 1 + k;
        cc = cc < 0 ? 0 : (cc > 511 ? 511 : cc);
        scol[k] = cc + (cc >> 5);
    }

    float acc0 = 0.f, acc1 = 0.f, acc2 = 0.f, acc3 = 0.f;
    #pragma unroll
    for (int j = 0; j < 4; j++) {
        const float* rp = lds + (2 * w + j) * LSTRIDE;
        float r0 = rp[scol[0]], r1 = rp[scol[1]], r2 = rp[scol[2]], r3 = rp[scol[3]], r4 = rp[scol[4]];
        float r5 = rp[scol[5]], r6 = rp[scol[6]], r7 = rp[scol[7]], r8 = rp[scol[8]], r9 = rp[scol[9]];
        float wj = (j == 0 || j == 3) ? w0 : w1;
        float h0 = w0 * r0 + w1 * r1 + w1 * r2 + w0 * r3;
        float h1 = w0 * r2 + w1 * r3 + w1 * r4 + w0 * r5;
        float h2 = w0 * r4 + w1 * r5 + w1 * r6 + w0 * r7;
        float h3 = w0 * r6 + w1 * r7 + w1 * r8 + w0 * r9;
        acc0 += wj * h0; acc1 += wj * h1; acc2 += wj * h2; acc3 += wj * h3;
    }

    int b   = bc >> 4;
    int cc_ = bc & 15;
    size_t rowoff = ((size_t)y << 8) + (size_t)x0;   // y*256 + x0
    const size_t P  = 65536;                          // 256*256
    const size_t HB = 16777216;                       // LL element count

    #pragma unroll
    for (int q = 0; q < 4; q++) {
        float f1g = (q & 1) ? sfl : sg;
        float f1h = (q & 1) ? sfh : sh;
        float f2g = (q & 2) ? sfl : sg;
        float f2h = (q & 2) ? sfh : sh;

        size_t chan = (size_t)(b * 64 + q * 16 + cc_);

        {
            float s = f1g * f2g;
            float4 v = make_float4(acc0 * s, acc1 * s, acc2 * s, acc3 * s);
            *(float4*)(out + chan * P + rowoff) = v;
        }
        size_t hbase = HB + chan * 3 * P + rowoff;
        {
            float s = f1g * f2h;
            float4 v = make_float4(acc0 * s, acc1 * s, acc2 * s, acc3 * s);
            *(float4*)(out + hbase) = v;
        }
        {
            float s = f1h * f2g;
            float4 v = make_float4(acc0 * s, acc1 * s, acc2 * s, acc3 * s);
            *(float4*)(out + hbase + P) = v;
        }
        {
            float s = f1h * f2h;
            float4 v = make_float4(acc0 * s, acc1 * s, acc2 * s, acc3 * s);
            *(float4*)(out + hbase + 2 * P) = v;
        }
    }
}

extern "C" void kernel_launch(void* const* d_in, const int* in_sizes, int n_in,
                              void* d_out, int out_size, void* d_ws, size_t ws_size,
                              hipStream_t stream) {
    const float* img = (const float*)d_in[0];
    const float* gl  = (const float*)d_in[1];
    const float* gh  = (const float*)d_in[2];
    const float* fl  = (const float*)d_in[3];
    const float* fh  = (const float*)d_in[4];
    float* out = (float*)d_out;
    float* ws  = (float*)d_ws;

    qwt_sums_kernel<<<1, 64, 0, stream>>>(gl, gh, fl, fh, ws);
    qwt_main_kernel<<<4096, 256, 0, stream>>>(img, ws, out);
}